// Round 1
// baseline (318.167 us; speedup 1.0000x reference)
//
#include <hip/hip_runtime.h>
#include <hip/hip_bf16.h>
#include <stdint.h>

typedef __attribute__((ext_vector_type(8))) short bf16x8;
typedef __attribute__((ext_vector_type(4))) short s16x4;
typedef __attribute__((ext_vector_type(4))) float f32x4;

__device__ __forceinline__ float bf2f(short s) {
    union { float f; uint32_t u; } v; v.u = ((uint32_t)(uint16_t)s) << 16; return v.f;
}
__device__ __forceinline__ short f2bf(float f) {
    union { float f; uint32_t u; } v; v.f = f;
    uint32_t u = v.u;
    u += 0x7FFFu + ((u >> 16) & 1u);   // round-nearest-even
    return (short)(u >> 16);
}
__device__ __forceinline__ void gload_lds16(const void* g, void* l) {
    __builtin_amdgcn_global_load_lds(
        (const __attribute__((address_space(1))) uint32_t*)g,
        (__attribute__((address_space(3))) uint32_t*)l, 16, 0, 0);
}

// ---------------- LayerNorm over rows of 128 (one wave per row) ----------------
// MODE 0: out_bf = LN(x)                      (Hn)
// MODE 1: out_f = out_bf = LN(x + res)        (O = LN2(preO + H))
// MODE 2: out_f = res + LN(x)                 (out = O + LN3(G2))
template<int MODE>
__global__ __launch_bounds__(256) void ln_kernel(
    const float* __restrict__ x, const float* __restrict__ res,
    const float* __restrict__ gamma, const float* __restrict__ beta,
    float* __restrict__ outf, short* __restrict__ outb)
{
    const int row = blockIdx.x * 4 + (threadIdx.x >> 6);
    const int lane = threadIdx.x & 63;
    const long base = (long)row * 128;
    float2 v = *(const float2*)(x + base + lane * 2);
    if (MODE == 1) {
        float2 rr = *(const float2*)(res + base + lane * 2);
        v.x += rr.x; v.y += rr.y;
    }
    float s = v.x + v.y, s2 = v.x * v.x + v.y * v.y;
#pragma unroll
    for (int o = 32; o; o >>= 1) { s += __shfl_xor(s, o); s2 += __shfl_xor(s2, o); }
    const float mean = s * (1.f / 128.f);
    const float var = s2 * (1.f / 128.f) - mean * mean;
    const float rs = rsqrtf(var + 1e-5f);
    const float y0 = (v.x - mean) * rs * gamma[lane * 2] + beta[lane * 2];
    const float y1 = (v.y - mean) * rs * gamma[lane * 2 + 1] + beta[lane * 2 + 1];
    if (MODE == 0 || MODE == 1) {
        uint32_t pk = (uint32_t)(uint16_t)f2bf(y0) | ((uint32_t)(uint16_t)f2bf(y1) << 16);
        *(uint32_t*)(outb + base + lane * 2) = pk;
    }
    if (MODE == 1) {
        float2 o2; o2.x = y0; o2.y = y1;
        *(float2*)(outf + base + lane * 2) = o2;
    }
    if (MODE == 2) {
        float2 rr = *(const float2*)(res + base + lane * 2);
        float2 o2; o2.x = y0 + rr.x; o2.y = y1 + rr.y;
        *(float2*)(outf + base + lane * 2) = o2;
    }
}

// ---------------- GCN degree: dis = rsqrt(max(rowsum(Ahat),1)) ----------------
__global__ __launch_bounds__(256) void dis_kernel(const float* __restrict__ A, float* __restrict__ dis)
{
    const int bn = blockIdx.x;          // b*1024 + n
    const int n = bn & 1023;
    float4 v = ((const float4*)(A + (long)bn * 1024))[threadIdx.x];
    float s = v.x + v.y + v.z + v.w;
    if ((n >> 2) == (int)threadIdx.x) { // diag: Ahat[n][n]=1 replaces A[n][n]
        s += 1.f - ((const float*)&v)[n & 3];
    }
#pragma unroll
    for (int o = 32; o; o >>= 1) s += __shfl_xor(s, o);
    __shared__ float red[4];
    if ((threadIdx.x & 63) == 0) red[threadIdx.x >> 6] = s;
    __syncthreads();
    if (threadIdx.x == 0) {
        float t = red[0] + red[1] + red[2] + red[3];
        dis[bn] = rsqrtf(fmaxf(t, 1.f));
    }
}

// ---------------- adj_bf16[b][n][m] = dis[n]*Ahat[n][m]*dis[m] ----------------
__global__ __launch_bounds__(256) void adjnorm_kernel(
    const float* __restrict__ A, const float* __restrict__ dis, short* __restrict__ adj)
{
    const int bn = blockIdx.x;
    const int b = bn >> 10, n = bn & 1023;
    const float dn = dis[bn];
    float4 v = ((const float4*)(A + (long)bn * 1024))[threadIdx.x];
    const int m0 = threadIdx.x * 4;
    const float* dm = dis + b * 1024 + m0;
    s16x4 o;
#pragma unroll
    for (int j = 0; j < 4; ++j) {
        float av = (m0 + j == n) ? 1.f : ((const float*)&v)[j];
        o[j] = f2bf(av * dn * dm[j]);
    }
    *(s16x4*)(adj + (long)bn * 1024 + m0) = o;
}

// ---------------- B_bias fp32 -> bf16 ----------------
__global__ __launch_bounds__(256) void bconv_kernel(const float* __restrict__ Bb, short* __restrict__ bb)
{
    const long i = ((long)blockIdx.x * 256 + threadIdx.x) * 4;
    float4 v = *(const float4*)(Bb + i);
    s16x4 o; o[0] = f2bf(v.x); o[1] = f2bf(v.y); o[2] = f2bf(v.z); o[3] = f2bf(v.w);
    *(s16x4*)(bb + i) = o;
}

// ---------------- weight conversion/transposes ----------------
__global__ __launch_bounds__(256) void convw_kernel(
    const float* __restrict__ WQ, const float* __restrict__ WK, const float* __restrict__ WV,
    const float* __restrict__ bQ, const float* __restrict__ bK, const float* __restrict__ bV,
    const float* __restrict__ WO, const float* __restrict__ W1, const float* __restrict__ W2,
    short* __restrict__ WqkvT, float* __restrict__ bqkv, short* __restrict__ WoT,
    short* __restrict__ W1T, short* __restrict__ W2T)
{
    const int id = blockIdx.x * 256 + threadIdx.x;
    if (id < 393216) {                      // WqkvT[f][k] = W_sel[k][f%1024]
        const int f = id >> 7, k = id & 127;
        const float* W = (f < 1024) ? WQ : (f < 2048 ? WK : WV);
        WqkvT[id] = f2bf(W[k * 1024 + (f & 1023)]);
    } else if (id < 396288) {
        const int f = id - 393216;
        const float* bb = (f < 1024) ? bQ : (f < 2048 ? bK : bV);
        bqkv[f] = bb[f & 1023];
    } else if (id < 527360) {               // WoT[j][i] = WO[i][j]
        const int t = id - 396288;
        const int j = t >> 10, i = t & 1023;
        WoT[t] = f2bf(WO[i * 128 + j]);
    } else if (id < 543744) {
        const int t = id - 527360;
        W1T[t] = f2bf(W1[(t & 127) * 128 + (t >> 7)]);
    } else if (id < 560128) {
        const int t = id - 543744;
        W2T[t] = f2bf(W2[(t & 127) * 128 + (t >> 7)]);
    }
}

// ---------------- V transpose: VT[(b*8+h)*128 + d][n] = QKV[b][n][2048+h*128+d] ----------------
__global__ __launch_bounds__(256) void vtrans_kernel(const short* __restrict__ QKV, short* __restrict__ VT)
{
    const int bh = blockIdx.y;
    const int b = bh >> 3, h = bh & 7;
    const int n = blockIdx.x * 64 + (threadIdx.x & 63);
    const int w = threadIdx.x >> 6;
    const short* src = QKV + ((long)(b * 1024 + n) * 3072 + 2048 + h * 128);
    short* dst = VT + (long)bh * 128 * 1024 + n;
#pragma unroll
    for (int c = 0; c < 4; ++c) {
        bf16x8 v = *(const bf16x8*)(src + (w * 4 + c) * 8);
#pragma unroll
        for (int i = 0; i < 8; ++i)
            dst[(long)((w * 4 + c) * 8 + i) * 1024] = v[i];
    }
}

// ---------------- generic tiled GEMM: C[M,N] = A[M,K] * Bt[N,K]^T ----------------
// 128x128 tile, 4 waves, 16x16x32 bf16 MFMA, global_load_lds staging (m97 structure)
template<int BIAS_MODE /*0 none,1 per-col,2 per-row*/, bool RELU, bool OUT_BF16>
__global__ __launch_bounds__(256) void gemm_kernel(
    const short* __restrict__ A, const short* __restrict__ Bt,
    const float* __restrict__ bias, void* __restrict__ Cv,
    int K, int lda, int ldb, int ldc,
    long batchA, long batchB, long batchC)
{
    __shared__ short Asm[128 * 32];
    __shared__ short Bsm[128 * 32];
    const int tid = threadIdx.x, lane = tid & 63, wave = tid >> 6;
    const int li = lane & 15, g = lane >> 4;
    const int mt = blockIdx.y * 128, nt = blockIdx.x * 128;
    A += (long)blockIdx.z * batchA;
    Bt += (long)blockIdx.z * batchB;

    const int wr = (wave >> 1) * 64, wc = (wave & 1) * 64;
    f32x4 acc[4][4] = {};

    const int srow = lane >> 2;          // 0..15
    const int scol = (lane & 3) * 8;     // 0,8,16,24 shorts
    const long aoff0 = (long)(mt + wave * 32 + srow) * lda + scol;
    const long aoff1 = aoff0 + (long)16 * lda;
    const long boff0 = (long)(nt + wave * 32 + srow) * ldb + scol;
    const long boff1 = boff0 + (long)16 * ldb;
    short* ad0 = &Asm[wave * 1024];
    short* ad1 = &Asm[wave * 1024 + 512];
    short* bd0 = &Bsm[wave * 1024];
    short* bd1 = &Bsm[wave * 1024 + 512];

    for (int k0 = 0; k0 < K; k0 += 32) {
        gload_lds16(A + aoff0 + k0, ad0);
        gload_lds16(A + aoff1 + k0, ad1);
        gload_lds16(Bt + boff0 + k0, bd0);
        gload_lds16(Bt + boff1 + k0, bd1);
        __syncthreads();
        bf16x8 af[4], bf[4];
#pragma unroll
        for (int m = 0; m < 4; ++m) af[m] = *(const bf16x8*)&Asm[(wr + m * 16 + li) * 32 + g * 8];
#pragma unroll
        for (int n = 0; n < 4; ++n) bf[n] = *(const bf16x8*)&Bsm[(wc + n * 16 + li) * 32 + g * 8];
#pragma unroll
        for (int m = 0; m < 4; ++m)
#pragma unroll
            for (int n = 0; n < 4; ++n)
                acc[m][n] = __builtin_amdgcn_mfma_f32_16x16x32_bf16(af[m], bf[n], acc[m][n], 0, 0, 0);
        __syncthreads();
    }

    const long cbase = (long)blockIdx.z * batchC;
#pragma unroll
    for (int m = 0; m < 4; ++m) {
        const int row0 = mt + wr + m * 16 + g * 4;
#pragma unroll
        for (int n = 0; n < 4; ++n) {
            const int col = nt + wc + n * 16 + li;
            float bc = (BIAS_MODE == 1) ? bias[col] : 0.f;
#pragma unroll
            for (int r = 0; r < 4; ++r) {
                float x = acc[m][n][r] + bc;
                if (BIAS_MODE == 2) x += bias[row0 + r];
                if (RELU) x = fmaxf(x, 0.f);
                const long idx = cbase + (long)(row0 + r) * ldc + col;
                if (OUT_BF16) ((short*)Cv)[idx] = f2bf(x);
                else          ((float*)Cv)[idx] = x;
            }
        }
    }
}

// ---------------- fused flash attention + bias + LN1 ----------------
__global__ __launch_bounds__(256) void attn_kernel(
    const short* __restrict__ QKV, const short* __restrict__ VT,
    const short* __restrict__ biasb,
    const float* __restrict__ g1v, const float* __restrict__ be1v,
    short* __restrict__ MHc)
{
    const int tid = threadIdx.x;
    const int lane = tid & 63;
    const int wave = tid >> 6;
    const int li = lane & 15;
    const int g = lane >> 4;
    const int qt = blockIdx.x * 128;
    const int h = blockIdx.y;
    const int b = blockIdx.z;

    __shared__ short Ksm[32 * 128];        // [kv][d], XOR-swizzled 16B chunks
    __shared__ short Vsm[128 * 32];        // [d][kv] (from VT, linear)
    __shared__ short Psm[4][32 * 40];      // per-wave P [32q][32kv], ld=40

    bf16x8 qf[2][4];
    {
        const short* Qb = QKV + ((long)(b * 1024 + qt + wave * 32) * 3072 + h * 128);
#pragma unroll
        for (int m = 0; m < 2; ++m)
#pragma unroll
            for (int dc = 0; dc < 4; ++dc)
                qf[m][dc] = *(const bf16x8*)(Qb + (long)(m * 16 + li) * 3072 + dc * 32 + g * 8);
    }

    float mrun[2][4], lrun[2][4];
    f32x4 oacc[2][8] = {};
#pragma unroll
    for (int m = 0; m < 2; ++m)
#pragma unroll
        for (int r = 0; r < 4; ++r) { mrun[m][r] = -1e30f; lrun[m][r] = 0.f; }

    const int kr0 = wave * 8 + g;
    const int kr1 = wave * 8 + 4 + g;
    const long kbase = (long)(b * 1024) * 3072 + 1024 + h * 128;
    const int kc0 = ((li * 16) ^ ((kr0 & 7) << 4)) >> 1;   // pre-swizzled source col (shorts)
    const int kc1 = ((li * 16) ^ ((kr1 & 7) << 4)) >> 1;
    const long vbase = ((long)(b * 8 + h) * 128 + (lane >> 2)) * 1024 + (lane & 3) * 8;
    const float scale = 0.08838834764831845f;   // 1/sqrt(128)

    for (int kv0 = 0; kv0 < 1024; kv0 += 32) {
        gload_lds16(QKV + kbase + (long)(kv0 + kr0) * 3072 + kc0, &Ksm[(wave * 2 + 0) * 512]);
        gload_lds16(QKV + kbase + (long)(kv0 + kr1) * 3072 + kc1, &Ksm[(wave * 2 + 1) * 512]);
        gload_lds16(VT + vbase + (long)((wave * 2 + 0) * 16) * 1024 + kv0, &Vsm[(wave * 2 + 0) * 512]);
        gload_lds16(VT + vbase + (long)((wave * 2 + 1) * 16) * 1024 + kv0, &Vsm[(wave * 2 + 1) * 512]);
        __syncthreads();

        const f32x4 fz = {0.f, 0.f, 0.f, 0.f};
        f32x4 sacc[2][2] = {{fz, fz}, {fz, fz}};
#pragma unroll
        for (int j = 0; j < 2; ++j) {
            const int r = j * 16 + li;
            const int sw = (r & 7) << 4;
#pragma unroll
            for (int dc = 0; dc < 4; ++dc) {
                bf16x8 kf = *(const bf16x8*)((const char*)Ksm + r * 256 + ((dc * 64 + g * 16) ^ sw));
                sacc[0][j] = __builtin_amdgcn_mfma_f32_16x16x32_bf16(qf[0][dc], kf, sacc[0][j], 0, 0, 0);
                sacc[1][j] = __builtin_amdgcn_mfma_f32_16x16x32_bf16(qf[1][dc], kf, sacc[1][j], 0, 0, 0);
            }
        }

        const long bbase = ((long)h * 1024 + qt + wave * 32) * 1024 + kv0;
#pragma unroll
        for (int m = 0; m < 2; ++m) {
#pragma unroll
            for (int r = 0; r < 4; ++r) {
                const int qloc = m * 16 + g * 4 + r;
                float s0 = sacc[m][0][r] * scale + bf2f(biasb[bbase + (long)qloc * 1024 + li]);
                float s1 = sacc[m][1][r] * scale + bf2f(biasb[bbase + (long)qloc * 1024 + 16 + li]);
                float mx = fmaxf(s0, s1);
#pragma unroll
                for (int o = 1; o < 16; o <<= 1) mx = fmaxf(mx, __shfl_xor(mx, o));
                const float mnew = fmaxf(mrun[m][r], mx);
                const float corr = __expf(mrun[m][r] - mnew);
                const float p0 = __expf(s0 - mnew);
                const float p1 = __expf(s1 - mnew);
                float ps = p0 + p1;
#pragma unroll
                for (int o = 1; o < 16; o <<= 1) ps += __shfl_xor(ps, o);
                lrun[m][r] = lrun[m][r] * corr + ps;
                mrun[m][r] = mnew;
#pragma unroll
                for (int df = 0; df < 8; ++df) oacc[m][df][r] *= corr;
                short* pp = &Psm[wave][qloc * 40];
                pp[li] = f2bf(p0);
                pp[16 + li] = f2bf(p1);
            }
        }

        bf16x8 pf0 = *(const bf16x8*)&Psm[wave][li * 40 + g * 8];
        bf16x8 pf1 = *(const bf16x8*)&Psm[wave][(16 + li) * 40 + g * 8];
#pragma unroll
        for (int df = 0; df < 8; ++df) {
            bf16x8 vf = *(const bf16x8*)&Vsm[(df * 16 + li) * 32 + g * 8];
            oacc[0][df] = __builtin_amdgcn_mfma_f32_16x16x32_bf16(pf0, vf, oacc[0][df], 0, 0, 0);
            oacc[1][df] = __builtin_amdgcn_mfma_f32_16x16x32_bf16(pf1, vf, oacc[1][df], 0, 0, 0);
        }
        __syncthreads();
    }

    // epilogue: softmax-normalize (BEFORE LN — eps is not scale-invariant), LN1, store bf16
#pragma unroll
    for (int m = 0; m < 2; ++m) {
#pragma unroll
        for (int r = 0; r < 4; ++r) {
            const int qloc = m * 16 + g * 4 + r;
            const float inv = 1.f / lrun[m][r];
            float vals[8];
            float s1 = 0.f, s2 = 0.f;
#pragma unroll
            for (int df = 0; df < 8; ++df) {
                float v = oacc[m][df][r] * inv;
                vals[df] = v; s1 += v; s2 += v * v;
            }
#pragma unroll
            for (int o = 1; o < 16; o <<= 1) { s1 += __shfl_xor(s1, o); s2 += __shfl_xor(s2, o); }
            const float mean = s1 * (1.f / 128.f);
            const float var = s2 * (1.f / 128.f) - mean * mean;
            const float rs = rsqrtf(var + 1e-5f);
            const long orow = (long)(b * 1024 + qt + wave * 32 + qloc) * 1024 + h * 128;
#pragma unroll
            for (int df = 0; df < 8; ++df) {
                const int d = df * 16 + li;
                MHc[orow + d] = f2bf((vals[df] - mean) * rs * g1v[d] + be1v[d]);
            }
        }
    }
}

// ---------------- launch ----------------
extern "C" void kernel_launch(void* const* d_in, const int* in_sizes, int n_in,
                              void* d_out, int out_size, void* d_ws, size_t ws_size,
                              hipStream_t stream)
{
    const float* H  = (const float*)d_in[0];
    const float* A  = (const float*)d_in[1];
    const float* WQ = (const float*)d_in[2];
    const float* bQ = (const float*)d_in[3];
    const float* WK = (const float*)d_in[4];
    const float* bK = (const float*)d_in[5];
    const float* WV = (const float*)d_in[6];
    const float* bV = (const float*)d_in[7];
    const float* Bb = (const float*)d_in[8];
    const float* WO = (const float*)d_in[9];
    const float* g0 = (const float*)d_in[10]; const float* be0 = (const float*)d_in[11];
    const float* g1 = (const float*)d_in[12]; const float* be1 = (const float*)d_in[13];
    const float* g2 = (const float*)d_in[14]; const float* be2 = (const float*)d_in[15];
    const float* g3 = (const float*)d_in[16]; const float* be3 = (const float*)d_in[17];
    const float* W1 = (const float*)d_in[18]; const float* b1 = (const float*)d_in[19];
    const float* W2 = (const float*)d_in[20]; const float* b2 = (const float*)d_in[21];
    float* out = (float*)d_out;

    char* ws = (char*)d_ws;
    short* Hn    = (short*)(ws + 0);
    short* adj   = (short*)(ws + 2097152);
    float* dis   = (float*)(ws + 18874368);
    short* WqkvT = (short*)(ws + 18907136);
    float* bqkv  = (float*)(ws + 19693568);
    short* WoT   = (short*)(ws + 19705856);
    short* W1T   = (short*)(ws + 19968000);
    short* W2T   = (short*)(ws + 20000768);
    short* biasb = (short*)(ws + 20033536);
    short* QKV   = (short*)(ws + 36810752);
    short* XWT   = (short*)(ws + 87142400);
    short* VT    = adj;    // adj dead after GCN gemm
    short* MHc   = XWT;    // XWT dead after GCN gemm
    float* preO  = (float*)(ws + 103919616);
    float* O     = (float*)(ws + 108113920);
    short* Obf   = (short*)(ws + 112308224);
    short* G1    = (short*)(ws + 114405376);
    float* G2    = (float*)(ws + 116502528);

    // prep
    ln_kernel<0><<<2048, 256, 0, stream>>>(H, nullptr, g0, be0, nullptr, Hn);
    dis_kernel<<<8192, 256, 0, stream>>>(A, dis);
    adjnorm_kernel<<<8192, 256, 0, stream>>>(A, dis, adj);
    bconv_kernel<<<8192, 256, 0, stream>>>(Bb, biasb);
    convw_kernel<<<2188, 256, 0, stream>>>(WQ, WK, WV, bQ, bK, bV, WO, W1, W2,
                                           WqkvT, bqkv, WoT, W1T, W2T);
    // XW_T[f][bn] = sum_k WqkvT[f][k]*Hn[bn][k]   (M=3072,N=8192,K=128)
    gemm_kernel<0, false, true><<<dim3(64, 24, 1), 256, 0, stream>>>(
        WqkvT, Hn, nullptr, XWT, 128, 128, 128, 8192, 0, 0, 0);
    // QKV[b][n][f] = sum_m adj[b][n][m]*XW[b][m][f] + bqkv[f]  (M=1024,N=3072,K=1024,B=8)
    gemm_kernel<1, false, true><<<dim3(24, 8, 8), 256, 0, stream>>>(
        adj, XWT, bqkv, QKV, 1024, 1024, 8192, 3072,
        1024L * 1024, 1024, 1024L * 3072);
    vtrans_kernel<<<dim3(16, 64), 256, 0, stream>>>(QKV, VT);
    attn_kernel<<<dim3(8, 8, 8), 256, 0, stream>>>(QKV, VT, biasb, g1, be1, MHc);
    // preO = MHc @ WO   (M=8192,N=128,K=1024)
    gemm_kernel<0, false, false><<<dim3(1, 64, 1), 256, 0, stream>>>(
        MHc, WoT, nullptr, preO, 1024, 1024, 1024, 128, 0, 0, 0);
    ln_kernel<1><<<2048, 256, 0, stream>>>(preO, H, g2, be2, O, Obf);
    // G1 = relu(O@W1+b1), G2 = relu(G1@W2+b2)
    gemm_kernel<1, true, true><<<dim3(1, 64, 1), 256, 0, stream>>>(
        Obf, W1T, b1, G1, 128, 128, 128, 128, 0, 0, 0);
    gemm_kernel<1, true, false><<<dim3(1, 64, 1), 256, 0, stream>>>(
        G1, W2T, b2, G2, 128, 128, 128, 128, 0, 0, 0);
    ln_kernel<2><<<2048, 256, 0, stream>>>(G2, O, g3, be3, out, nullptr);
}

// Round 2
// 267.841 us; speedup vs baseline: 1.1879x; 1.1879x over previous
//
#include <hip/hip_runtime.h>
#include <hip/hip_bf16.h>
#include <stdint.h>

typedef __attribute__((ext_vector_type(8))) short bf16x8;
typedef __attribute__((ext_vector_type(4))) short s16x4;
typedef __attribute__((ext_vector_type(4))) float f32x4;

__device__ __forceinline__ float bf2f(short s) {
    union { float f; uint32_t u; } v; v.u = ((uint32_t)(uint16_t)s) << 16; return v.f;
}
__device__ __forceinline__ short f2bf(float f) {
    union { float f; uint32_t u; } v; v.f = f;
    uint32_t u = v.u;
    u += 0x7FFFu + ((u >> 16) & 1u);   // round-nearest-even
    return (short)(u >> 16);
}
__device__ __forceinline__ void gload_lds16(const void* g, void* l) {
    __builtin_amdgcn_global_load_lds(
        (const __attribute__((address_space(1))) uint32_t*)g,
        (__attribute__((address_space(3))) uint32_t*)l, 16, 0, 0);
}

// ---------------- LayerNorm over rows of 128 (one wave per row) ----------------
template<int MODE>
__global__ __launch_bounds__(256) void ln_kernel(
    const float* __restrict__ x, const float* __restrict__ res,
    const float* __restrict__ gamma, const float* __restrict__ beta,
    float* __restrict__ outf, short* __restrict__ outb)
{
    const int row = blockIdx.x * 4 + (threadIdx.x >> 6);
    const int lane = threadIdx.x & 63;
    const long base = (long)row * 128;
    float2 v = *(const float2*)(x + base + lane * 2);
    if (MODE == 1) {
        float2 rr = *(const float2*)(res + base + lane * 2);
        v.x += rr.x; v.y += rr.y;
    }
    float s = v.x + v.y, s2 = v.x * v.x + v.y * v.y;
#pragma unroll
    for (int o = 32; o; o >>= 1) { s += __shfl_xor(s, o); s2 += __shfl_xor(s2, o); }
    const float mean = s * (1.f / 128.f);
    const float var = s2 * (1.f / 128.f) - mean * mean;
    const float rs = rsqrtf(var + 1e-5f);
    const float y0 = (v.x - mean) * rs * gamma[lane * 2] + beta[lane * 2];
    const float y1 = (v.y - mean) * rs * gamma[lane * 2 + 1] + beta[lane * 2 + 1];
    if (MODE == 0 || MODE == 1) {
        uint32_t pk = (uint32_t)(uint16_t)f2bf(y0) | ((uint32_t)(uint16_t)f2bf(y1) << 16);
        *(uint32_t*)(outb + base + lane * 2) = pk;
    }
    if (MODE == 1) {
        float2 o2; o2.x = y0; o2.y = y1;
        *(float2*)(outf + base + lane * 2) = o2;
    }
    if (MODE == 2) {
        float2 rr = *(const float2*)(res + base + lane * 2);
        float2 o2; o2.x = y0 + rr.x; o2.y = y1 + rr.y;
        *(float2*)(outf + base + lane * 2) = o2;
    }
}

// ---------------- GCN degree: dis = rsqrt(max(rowsum(Ahat),1)) ----------------
__global__ __launch_bounds__(256) void dis_kernel(const float* __restrict__ A, float* __restrict__ dis)
{
    const int bn = blockIdx.x;
    const int n = bn & 1023;
    float4 v = ((const float4*)(A + (long)bn * 1024))[threadIdx.x];
    float s = v.x + v.y + v.z + v.w;
    if ((n >> 2) == (int)threadIdx.x) {
        s += 1.f - ((const float*)&v)[n & 3];
    }
#pragma unroll
    for (int o = 32; o; o >>= 1) s += __shfl_xor(s, o);
    __shared__ float red[4];
    if ((threadIdx.x & 63) == 0) red[threadIdx.x >> 6] = s;
    __syncthreads();
    if (threadIdx.x == 0) {
        float t = red[0] + red[1] + red[2] + red[3];
        dis[bn] = rsqrtf(fmaxf(t, 1.f));
    }
}

// ---------------- adj_bf16[b][n][m] = dis[n]*Ahat[n][m]*dis[m] ----------------
__global__ __launch_bounds__(256) void adjnorm_kernel(
    const float* __restrict__ A, const float* __restrict__ dis, short* __restrict__ adj)
{
    const int bn = blockIdx.x;
    const int b = bn >> 10, n = bn & 1023;
    const float dn = dis[bn];
    float4 v = ((const float4*)(A + (long)bn * 1024))[threadIdx.x];
    const int m0 = threadIdx.x * 4;
    const float* dm = dis + b * 1024 + m0;
    s16x4 o;
#pragma unroll
    for (int j = 0; j < 4; ++j) {
        float av = (m0 + j == n) ? 1.f : ((const float*)&v)[j];
        o[j] = f2bf(av * dn * dm[j]);
    }
    *(s16x4*)(adj + (long)bn * 1024 + m0) = o;
}

// ---------------- B_bias fp32 -> bf16 ----------------
__global__ __launch_bounds__(256) void bconv_kernel(const float* __restrict__ Bb, short* __restrict__ bb)
{
    const long i = ((long)blockIdx.x * 256 + threadIdx.x) * 4;
    float4 v = *(const float4*)(Bb + i);
    s16x4 o; o[0] = f2bf(v.x); o[1] = f2bf(v.y); o[2] = f2bf(v.z); o[3] = f2bf(v.w);
    *(s16x4*)(bb + i) = o;
}

// ---------------- weight conversion/transposes ----------------
__global__ __launch_bounds__(256) void convw_kernel(
    const float* __restrict__ WQ, const float* __restrict__ WK, const float* __restrict__ WV,
    const float* __restrict__ bQ, const float* __restrict__ bK, const float* __restrict__ bV,
    const float* __restrict__ WO, const float* __restrict__ W1, const float* __restrict__ W2,
    short* __restrict__ WqkvT, float* __restrict__ bqkv, short* __restrict__ WoT,
    short* __restrict__ W1T, short* __restrict__ W2T)
{
    const int id = blockIdx.x * 256 + threadIdx.x;
    if (id < 393216) {
        const int f = id >> 7, k = id & 127;
        const float* W = (f < 1024) ? WQ : (f < 2048 ? WK : WV);
        WqkvT[id] = f2bf(W[k * 1024 + (f & 1023)]);
    } else if (id < 396288) {
        const int f = id - 393216;
        const float* bb = (f < 1024) ? bQ : (f < 2048 ? bK : bV);
        bqkv[f] = bb[f & 1023];
    } else if (id < 527360) {
        const int t = id - 396288;
        const int j = t >> 10, i = t & 1023;
        WoT[t] = f2bf(WO[i * 128 + j]);
    } else if (id < 543744) {
        const int t = id - 527360;
        W1T[t] = f2bf(W1[(t & 127) * 128 + (t >> 7)]);
    } else if (id < 560128) {
        const int t = id - 543744;
        W2T[t] = f2bf(W2[(t & 127) * 128 + (t >> 7)]);
    }
}

// ---------------- V transpose: VT[(b*8+h)*128 + d][n] ----------------
__global__ __launch_bounds__(256) void vtrans_kernel(const short* __restrict__ QKV, short* __restrict__ VT)
{
    const int bh = blockIdx.y;
    const int b = bh >> 3, h = bh & 7;
    const int n = blockIdx.x * 64 + (threadIdx.x & 63);
    const int w = threadIdx.x >> 6;
    const short* src = QKV + ((long)(b * 1024 + n) * 3072 + 2048 + h * 128);
    short* dst = VT + (long)bh * 128 * 1024 + n;
#pragma unroll
    for (int c = 0; c < 4; ++c) {
        bf16x8 v = *(const bf16x8*)(src + (w * 4 + c) * 8);
#pragma unroll
        for (int i = 0; i < 8; ++i)
            dst[(long)((w * 4 + c) * 8 + i) * 1024] = v[i];
    }
}

// ---------------- 128x128 tiled GEMM: C[M,N] = A[M,K] * Bt[N,K]^T ----------------
template<int BIAS_MODE, bool RELU, bool OUT_BF16>
__global__ __launch_bounds__(256) void gemm_kernel(
    const short* __restrict__ A, const short* __restrict__ Bt,
    const float* __restrict__ bias, void* __restrict__ Cv,
    int K, int lda, int ldb, int ldc,
    long batchA, long batchB, long batchC)
{
    __shared__ __align__(16) short Asm[128 * 32];
    __shared__ __align__(16) short Bsm[128 * 32];
    const int tid = threadIdx.x, lane = tid & 63, wave = tid >> 6;
    const int li = lane & 15, g = lane >> 4;
    const int mt = blockIdx.y * 128, nt = blockIdx.x * 128;
    A += (long)blockIdx.z * batchA;
    Bt += (long)blockIdx.z * batchB;

    const int wr = (wave >> 1) * 64, wc = (wave & 1) * 64;
    f32x4 acc[4][4] = {};

    const int srow = lane >> 2;
    const int scol = (lane & 3) * 8;
    const long aoff0 = (long)(mt + wave * 32 + srow) * lda + scol;
    const long aoff1 = aoff0 + (long)16 * lda;
    const long boff0 = (long)(nt + wave * 32 + srow) * ldb + scol;
    const long boff1 = boff0 + (long)16 * ldb;
    short* ad0 = &Asm[wave * 1024];
    short* ad1 = &Asm[wave * 1024 + 512];
    short* bd0 = &Bsm[wave * 1024];
    short* bd1 = &Bsm[wave * 1024 + 512];

    for (int k0 = 0; k0 < K; k0 += 32) {
        gload_lds16(A + aoff0 + k0, ad0);
        gload_lds16(A + aoff1 + k0, ad1);
        gload_lds16(Bt + boff0 + k0, bd0);
        gload_lds16(Bt + boff1 + k0, bd1);
        __syncthreads();
        bf16x8 af[4], bf[4];
#pragma unroll
        for (int m = 0; m < 4; ++m) af[m] = *(const bf16x8*)&Asm[(wr + m * 16 + li) * 32 + g * 8];
#pragma unroll
        for (int n = 0; n < 4; ++n) bf[n] = *(const bf16x8*)&Bsm[(wc + n * 16 + li) * 32 + g * 8];
#pragma unroll
        for (int m = 0; m < 4; ++m)
#pragma unroll
            for (int n = 0; n < 4; ++n)
                acc[m][n] = __builtin_amdgcn_mfma_f32_16x16x32_bf16(af[m], bf[n], acc[m][n], 0, 0, 0);
        __syncthreads();
    }

    const long cbase = (long)blockIdx.z * batchC;
#pragma unroll
    for (int m = 0; m < 4; ++m) {
        const int row0 = mt + wr + m * 16 + g * 4;
#pragma unroll
        for (int n = 0; n < 4; ++n) {
            const int col = nt + wc + n * 16 + li;
            float bc = (BIAS_MODE == 1) ? bias[col] : 0.f;
#pragma unroll
            for (int r = 0; r < 4; ++r) {
                float x = acc[m][n][r] + bc;
                if (RELU) x = fmaxf(x, 0.f);
                const long idx = cbase + (long)(row0 + r) * ldc + col;
                if (OUT_BF16) ((short*)Cv)[idx] = f2bf(x);
                else          ((float*)Cv)[idx] = x;
            }
        }
    }
}

// ---------------- 64x64 tiled GEMM (for skinny-N, high-parallelism cases) ----------------
template<int BIAS_MODE, bool RELU, bool OUT_BF16>
__global__ __launch_bounds__(256) void gemm64_kernel(
    const short* __restrict__ A, const short* __restrict__ Bt,
    const float* __restrict__ bias, void* __restrict__ Cv,
    int K, int lda, int ldb, int ldc)
{
    __shared__ __align__(16) short Asm[64 * 32];
    __shared__ __align__(16) short Bsm[64 * 32];
    const int tid = threadIdx.x, lane = tid & 63, wave = tid >> 6;
    const int li = lane & 15, g = lane >> 4;
    const int mt = blockIdx.y * 64, nt = blockIdx.x * 64;
    const int wr = (wave >> 1) * 32, wc = (wave & 1) * 32;
    f32x4 acc[2][2] = {};

    const int srow = lane >> 2;
    const int scol = (lane & 3) * 8;
    const long aoff = (long)(mt + wave * 16 + srow) * lda + scol;
    const long boff = (long)(nt + wave * 16 + srow) * ldb + scol;

    for (int k0 = 0; k0 < K; k0 += 32) {
        gload_lds16(A + aoff + k0, &Asm[wave * 512]);
        gload_lds16(Bt + boff + k0, &Bsm[wave * 512]);
        __syncthreads();
        bf16x8 af[2], bf[2];
#pragma unroll
        for (int m = 0; m < 2; ++m) af[m] = *(const bf16x8*)&Asm[(wr + m * 16 + li) * 32 + g * 8];
#pragma unroll
        for (int n = 0; n < 2; ++n) bf[n] = *(const bf16x8*)&Bsm[(wc + n * 16 + li) * 32 + g * 8];
#pragma unroll
        for (int m = 0; m < 2; ++m)
#pragma unroll
            for (int n = 0; n < 2; ++n)
                acc[m][n] = __builtin_amdgcn_mfma_f32_16x16x32_bf16(af[m], bf[n], acc[m][n], 0, 0, 0);
        __syncthreads();
    }

#pragma unroll
    for (int m = 0; m < 2; ++m) {
        const int row0 = mt + wr + m * 16 + g * 4;
#pragma unroll
        for (int n = 0; n < 2; ++n) {
            const int col = nt + wc + n * 16 + li;
            float bc = (BIAS_MODE == 1) ? bias[col] : 0.f;
#pragma unroll
            for (int r = 0; r < 4; ++r) {
                float x = acc[m][n][r] + bc;
                if (RELU) x = fmaxf(x, 0.f);
                const long idx = (long)(row0 + r) * ldc + col;
                if (OUT_BF16) ((short*)Cv)[idx] = f2bf(x);
                else          ((float*)Cv)[idx] = x;
            }
        }
    }
}

// ---------------- fused flash attention + bias + LN1 ----------------
// 512 threads = 8 waves; each wave owns 16 q rows; kv-step 64; defer-max.
// grid 1D 512: h = id&7 (XCD affinity), b = (id>>3)&7, qt = id>>6.
__global__ __launch_bounds__(512, 4) void attn_kernel(
    const short* __restrict__ QKV, const short* __restrict__ VT,
    const short* __restrict__ biasb,
    const float* __restrict__ g1v, const float* __restrict__ be1v,
    short* __restrict__ MHc)
{
    const int tid = threadIdx.x;
    const int lane = tid & 63;
    const int wave = tid >> 6;          // 0..7
    const int li = lane & 15;
    const int g = lane >> 4;

    const int id = blockIdx.x;
    const int h = id & 7;
    const int b = (id >> 3) & 7;
    const int qt = id >> 6;             // 0..7
    const int q0 = qt * 128;

    __shared__ __align__(16) short Ksm[64 * 128];     // [kv][d] XOR-swizzled
    __shared__ __align__(16) short Vsm[128 * 64];     // [d][kv] XOR-swizzled
    __shared__ __align__(16) short Psm[8][16 * 72];   // per-wave P [16 q][64 kv], ld=72

    // Q fragments: wave handles q rows q0 + wave*16 .. +15 (row = li)
    bf16x8 qf[4];
    {
        const short* Qb = QKV + ((long)(b * 1024 + q0 + wave * 16 + li) * 3072 + h * 128);
#pragma unroll
        for (int dc = 0; dc < 4; ++dc)
            qf[dc] = *(const bf16x8*)(Qb + dc * 32 + g * 8);
    }

    float mrun[4], lrun[4];
#pragma unroll
    for (int r = 0; r < 4; ++r) { mrun[r] = -1e30f; lrun[r] = 0.f; }
    f32x4 oacc[8] = {};

    const long kbase = (long)(b * 1024) * 3072 + 1024 + h * 128;
    const int kr0 = wave * 8 + g;            // K staging rows (c=0), +4 for c=1
    const int kc0 = ((li * 16) ^ ((kr0 & 7) << 4)) >> 1;
    const int kc1 = ((li * 16) ^ (((kr0 + 4) & 7) << 4)) >> 1;
    const int vd_loc = lane >> 3;            // 0..7  (d&7 within 8-row chunk)
    const int vcol = (((lane & 7) * 16) ^ (vd_loc << 4)) >> 1;
    const long vrowbase = ((long)(b * 8 + h) * 128) * 1024;

    const float scale = 0.08838834764831845f;     // 1/sqrt(128)
    const long bb_row0 = (long)h * 1024 + q0 + wave * 16;

    for (int kv0 = 0; kv0 < 1024; kv0 += 64) {
        gload_lds16(QKV + kbase + (long)(kv0 + kr0) * 3072 + kc0, &Ksm[wave * 1024]);
        gload_lds16(QKV + kbase + (long)(kv0 + kr0 + 4) * 3072 + kc1, &Ksm[wave * 1024 + 512]);
        gload_lds16(VT + vrowbase + (long)(wave * 16 + vd_loc) * 1024 + kv0 + vcol,
                    &Vsm[(wave * 16) * 64]);
        gload_lds16(VT + vrowbase + (long)(wave * 16 + 8 + vd_loc) * 1024 + kv0 + vcol,
                    &Vsm[(wave * 16 + 8) * 64]);
        __syncthreads();

        // QK^T: S[q=li-row][kv] for 4 kv j-blocks
        const f32x4 fz = {0.f, 0.f, 0.f, 0.f};
        f32x4 sacc[4] = {fz, fz, fz, fz};
#pragma unroll
        for (int j = 0; j < 4; ++j) {
            const int r = j * 16 + li;
            const int sw = (r & 7) << 4;
#pragma unroll
            for (int dc = 0; dc < 4; ++dc) {
                bf16x8 kf = *(const bf16x8*)((const char*)Ksm + r * 256 + ((dc * 64 + g * 16) ^ sw));
                sacc[j] = __builtin_amdgcn_mfma_f32_16x16x32_bf16(qf[dc], kf, sacc[j], 0, 0, 0);
            }
        }

        // streaming softmax with defer-max (THR=8)
#pragma unroll
        for (int r = 0; r < 4; ++r) {
            const int qloc = g * 4 + r;
            const short* bp = biasb + (bb_row0 + qloc) * 1024 + kv0 + li;
            float s[4];
#pragma unroll
            for (int j = 0; j < 4; ++j)
                s[j] = sacc[j][r] * scale + bf2f(bp[j * 16]);
            float mx = fmaxf(fmaxf(s[0], s[1]), fmaxf(s[2], s[3]));
#pragma unroll
            for (int o = 1; o < 16; o <<= 1) mx = fmaxf(mx, __shfl_xor(mx, o));
            if (__any(mx > mrun[r] + 8.f)) {
                const float mnew = fmaxf(mrun[r], mx);
                const float corr = __expf(mrun[r] - mnew);
                lrun[r] *= corr;
#pragma unroll
                for (int df = 0; df < 8; ++df) oacc[df][r] *= corr;
                mrun[r] = mnew;
            }
            float ps = 0.f;
            short* pp = &Psm[wave][qloc * 72];
#pragma unroll
            for (int j = 0; j < 4; ++j) {
                const float p = __expf(s[j] - mrun[r]);
                ps += p;
                pp[j * 16 + li] = f2bf(p);
            }
#pragma unroll
            for (int o = 1; o < 16; o <<= 1) ps += __shfl_xor(ps, o);
            lrun[r] += ps;
        }

        // PV: out[q][d] += P[q][kv] * V^T[d][kv]
#pragma unroll
        for (int c = 0; c < 2; ++c) {
            bf16x8 pf = *(const bf16x8*)((const char*)&Psm[wave][0] + li * 144 + c * 64 + g * 16);
#pragma unroll
            for (int df = 0; df < 8; ++df) {
                bf16x8 vf = *(const bf16x8*)((const char*)Vsm + (df * 16 + li) * 128
                                             + ((c * 64 + g * 16) ^ ((li & 7) << 4)));
                oacc[df] = __builtin_amdgcn_mfma_f32_16x16x32_bf16(pf, vf, oacc[df], 0, 0, 0);
            }
        }
        __syncthreads();
    }

    // epilogue: softmax-normalize, LN1, store bf16
#pragma unroll
    for (int r = 0; r < 4; ++r) {
        const int qloc = g * 4 + r;
        const float inv = 1.f / lrun[r];
        float vals[8];
        float s1 = 0.f, s2 = 0.f;
#pragma unroll
        for (int df = 0; df < 8; ++df) {
            float v = oacc[df][r] * inv;
            vals[df] = v; s1 += v; s2 += v * v;
        }
#pragma unroll
        for (int o = 1; o < 16; o <<= 1) { s1 += __shfl_xor(s1, o); s2 += __shfl_xor(s2, o); }
        const float mean = s1 * (1.f / 128.f);
        const float var = s2 * (1.f / 128.f) - mean * mean;
        const float rs = rsqrtf(var + 1e-5f);
        const long orow = (long)(b * 1024 + q0 + wave * 16 + qloc) * 1024 + h * 128;
#pragma unroll
        for (int df = 0; df < 8; ++df) {
            const int d = df * 16 + li;
            MHc[orow + d] = f2bf((vals[df] - mean) * rs * g1v[d] + be1v[d]);
        }
    }
}

// ---------------- launch ----------------
extern "C" void kernel_launch(void* const* d_in, const int* in_sizes, int n_in,
                              void* d_out, int out_size, void* d_ws, size_t ws_size,
                              hipStream_t stream)
{
    const float* H  = (const float*)d_in[0];
    const float* A  = (const float*)d_in[1];
    const float* WQ = (const float*)d_in[2];
    const float* bQ = (const float*)d_in[3];
    const float* WK = (const float*)d_in[4];
    const float* bK = (const float*)d_in[5];
    const float* WV = (const float*)d_in[6];
    const float* bV = (const float*)d_in[7];
    const float* Bb = (const float*)d_in[8];
    const float* WO = (const float*)d_in[9];
    const float* g0 = (const float*)d_in[10]; const float* be0 = (const float*)d_in[11];
    const float* g1 = (const float*)d_in[12]; const float* be1 = (const float*)d_in[13];
    const float* g2 = (const float*)d_in[14]; const float* be2 = (const float*)d_in[15];
    const float* g3 = (const float*)d_in[16]; const float* be3 = (const float*)d_in[17];
    const float* W1 = (const float*)d_in[18]; const float* b1 = (const float*)d_in[19];
    const float* W2 = (const float*)d_in[20]; const float* b2 = (const float*)d_in[21];
    float* out = (float*)d_out;

    char* ws = (char*)d_ws;
    short* Hn    = (short*)(ws + 0);
    short* adj   = (short*)(ws + 2097152);
    float* dis   = (float*)(ws + 18874368);
    short* WqkvT = (short*)(ws + 18907136);
    float* bqkv  = (float*)(ws + 19693568);
    short* WoT   = (short*)(ws + 19705856);
    short* W1T   = (short*)(ws + 19968000);
    short* W2T   = (short*)(ws + 20000768);
    short* biasb = (short*)(ws + 20033536);
    short* QKV   = (short*)(ws + 36810752);
    short* XWT   = (short*)(ws + 87142400);
    short* VT    = adj;    // adj dead after GCN gemm
    short* MHc   = XWT;    // XWT dead after GCN gemm
    float* preO  = (float*)(ws + 103919616);
    float* O     = (float*)(ws + 108113920);
    short* Obf   = (short*)(ws + 112308224);
    short* G1    = (short*)(ws + 114405376);
    float* G2    = (float*)(ws + 116502528);

    // prep
    ln_kernel<0><<<2048, 256, 0, stream>>>(H, nullptr, g0, be0, nullptr, Hn);
    dis_kernel<<<8192, 256, 0, stream>>>(A, dis);
    adjnorm_kernel<<<8192, 256, 0, stream>>>(A, dis, adj);
    bconv_kernel<<<8192, 256, 0, stream>>>(Bb, biasb);
    convw_kernel<<<2188, 256, 0, stream>>>(WQ, WK, WV, bQ, bK, bV, WO, W1, W2,
                                           WqkvT, bqkv, WoT, W1T, W2T);
    // XW_T[f][bn] = sum_k WqkvT[f][k]*Hn[bn][k]   (M=3072,N=8192,K=128)
    gemm_kernel<0, false, true><<<dim3(64, 24, 1), 256, 0, stream>>>(
        WqkvT, Hn, nullptr, XWT, 128, 128, 128, 8192, 0, 0, 0);
    // QKV[b][n][f] = sum_m adj[b][n][m]*XW[b][m][f] + bqkv[f]  (M=1024,N=3072,K=1024,B=8)
    gemm_kernel<1, false, true><<<dim3(24, 8, 8), 256, 0, stream>>>(
        adj, XWT, bqkv, QKV, 1024, 1024, 8192, 3072,
        1024L * 1024, 1024, 1024L * 3072);
    vtrans_kernel<<<dim3(16, 64), 256, 0, stream>>>(QKV, VT);
    attn_kernel<<<512, 512, 0, stream>>>(QKV, VT, biasb, g1, be1, MHc);
    // preO = MHc @ WO   (M=8192,N=128,K=1024) — 64x64 tiles for parallelism
    gemm64_kernel<0, false, false><<<dim3(2, 128), 256, 0, stream>>>(
        MHc, WoT, nullptr, preO, 1024, 1024, 1024, 128);
    ln_kernel<1><<<2048, 256, 0, stream>>>(preO, H, g2, be2, O, Obf);
    // G1 = relu(O@W1+b1), G2 = relu(G1@W2+b2)
    gemm64_kernel<1, true, true><<<dim3(2, 128), 256, 0, stream>>>(
        Obf, W1T, b1, G1, 128, 128, 128, 128);
    gemm64_kernel<1, true, false><<<dim3(2, 128), 256, 0, stream>>>(
        G1, W2T, b2, G2, 128, 128, 128, 128);
    ln_kernel<2><<<2048, 256, 0, stream>>>(G2, O, g3, be3, out, nullptr);
}